// Round 2
// baseline (16881.944 us; speedup 1.0000x reference)
//
#include <hip/hip_runtime.h>

#define TT 2048
#define WD 768
#define HH 512
#define G4 2048      // 4*H
#define NC 5
#define SENT 0xFFFFFFFFu   // owned sentinel (-NaN); |h|<1 can never produce it.
                           // h buffers memset to 0xFF at every launch.

typedef float f4 __attribute__((ext_vector_type(4)));
typedef unsigned int u4 __attribute__((ext_vector_type(4)));
typedef unsigned int u2 __attribute__((ext_vector_type(2)));

// ---------------------------------------------------------------------------
// Kernel 1: zin[t][g] = emb[sent[t]] . Wih[g] + bih[g] + bhh[g]   (both dirs)
// ---------------------------------------------------------------------------
__global__ __launch_bounds__(256) void zin_gemm(
    const int* __restrict__ sent, const float* __restrict__ emb,
    const float* __restrict__ Wih_f, const float* __restrict__ bih_f, const float* __restrict__ bhh_f,
    const float* __restrict__ Wih_b, const float* __restrict__ bih_b, const float* __restrict__ bhh_b,
    float* __restrict__ zin_f, float* __restrict__ zin_b)
{
    const int dirn = blockIdx.z;
    const float* Wih = dirn ? Wih_b : Wih_f;
    const float* bih = dirn ? bih_b : bih_f;
    const float* bhh = dirn ? bhh_b : bhh_f;
    float* zin = dirn ? zin_b : zin_f;

    __shared__ float As[16][128];
    __shared__ float Bs[16][128];

    const int tid = threadIdx.x;
    const int t0 = blockIdx.y * 128;
    const int g0 = blockIdx.x * 128;
    const int tm = tid >> 4, tn = tid & 15;

    float acc[8][8];
#pragma unroll
    for (int a = 0; a < 8; a++)
#pragma unroll
        for (int b = 0; b < 8; b++) acc[a][b] = 0.f;

    for (int kt = 0; kt < 48; ++kt) {
        const int k0 = kt * 16;
#pragma unroll
        for (int u = 0; u < 2; ++u) {
            const int s = tid * 2 + u;
            const int m = s >> 2, kq = s & 3;
            const int rowA = sent[t0 + m];
            float4 av = *(const float4*)(emb + (size_t)rowA * WD + k0 + kq * 4);
            As[kq * 4 + 0][m] = av.x; As[kq * 4 + 1][m] = av.y;
            As[kq * 4 + 2][m] = av.z; As[kq * 4 + 3][m] = av.w;
            float4 bv = *(const float4*)(Wih + (size_t)(g0 + m) * WD + k0 + kq * 4);
            Bs[kq * 4 + 0][m] = bv.x; Bs[kq * 4 + 1][m] = bv.y;
            Bs[kq * 4 + 2][m] = bv.z; Bs[kq * 4 + 3][m] = bv.w;
        }
        __syncthreads();
#pragma unroll
        for (int kk = 0; kk < 16; ++kk) {
            float4 a0 = *(const float4*)&As[kk][tm * 8];
            float4 a1 = *(const float4*)&As[kk][tm * 8 + 4];
            float4 b0 = *(const float4*)&Bs[kk][tn * 8];
            float4 b1 = *(const float4*)&Bs[kk][tn * 8 + 4];
            float av8[8] = {a0.x, a0.y, a0.z, a0.w, a1.x, a1.y, a1.z, a1.w};
            float bv8[8] = {b0.x, b0.y, b0.z, b0.w, b1.x, b1.y, b1.z, b1.w};
#pragma unroll
            for (int a = 0; a < 8; a++)
#pragma unroll
                for (int b = 0; b < 8; b++) acc[a][b] += av8[a] * bv8[b];
        }
        __syncthreads();
    }
    float bias[8];
#pragma unroll
    for (int b = 0; b < 8; b++) { int g = g0 + tn * 8 + b; bias[b] = bih[g] + bhh[g]; }
#pragma unroll
    for (int a = 0; a < 8; a++) {
        const int t = t0 + tm * 8 + a;
        float* op = zin + (size_t)t * G4 + g0 + tn * 8;
        float4 o0 = {acc[a][0] + bias[0], acc[a][1] + bias[1], acc[a][2] + bias[2], acc[a][3] + bias[3]};
        float4 o1 = {acc[a][4] + bias[4], acc[a][5] + bias[5], acc[a][6] + bias[6], acc[a][7] + bias[7]};
        *(float4*)op = o0; *(float4*)(op + 4) = o1;
    }
}

// ---------------------------------------------------------------------------
// Kernel 2: LSTM recurrence — XCD-local fast path v2 (atomic mailbox).
//
// R1 post-mortem: sc0-only loads are served by the STALE CU L1 (polls never
// see the store), and sc0-only stores strand dirty in the producer XCD's L2
// invisible to system-scope loads (the fallback read stale MALL). Both fixed:
//
//  * Producers DOUBLE-STORE each h word: plain store to hwl (write-through
//    L1 -> local XCD L2) then sc1 store to hw (MALL; the R0-proven path).
//  * Consumers' fast path polls hwl with RETURNING ATOMICS
//    (global_atomic_add_x2 +0, sc0=return-old). Atomics execute at the L2,
//    never the L1 -> no staleness. Same-XCD: L2-hit RT (~300cy). Cross-XCD:
//    miss pulls MALL (slow but never wrong).
//  * hwl is a SEPARATE buffer because add-0 atomics dirty lines; cross-XCD
//    dirty aliasing on hw could clobber real h values. hwl is scratch.
//  * One-shot classification at it==1: spin {fast-probe; base-probe}; if
//    base wins, re-probe fast once. Same-XCD: the plain store precedes the
//    sc1 store, so when MALL has the value the shared L2 must too ->
//    deterministically classified fast. Cross-XCD: the re-probe hits the
//    consumer's own cached sentinel line -> classified slow. Any later
//    anomaly: 16K-spin cap -> permanent fallback to the R0 protocol.
//
// Placement (unchanged from R1, it worked): 512 wgs, per-XCD slot claim via
// s_getreg(HW_REG_XCC_ID); first two complete groups of 32 same-XCD wgs
// become fwd/bwd; rest exit. Numerics bit-identical to R0.
// ---------------------------------------------------------------------------
__global__ __launch_bounds__(256, 1) void lstm_rec(
    const float* __restrict__ zin_f, const float* __restrict__ zin_b,
    const float* __restrict__ Whh_f, const float* __restrict__ Whh_b,
    unsigned int* __restrict__ hw_f, unsigned int* __restrict__ hw_b,
    unsigned int* __restrict__ hwl_f, unsigned int* __restrict__ hwl_b,
    unsigned int* __restrict__ ctl)
{
    // ---- XCD-local group claim (R1-proven) --------------------------------
    __shared__ int s_role;
    __shared__ int s_fast;
    if (threadIdx.x == 0) {
        unsigned int xcc;
        asm volatile("s_getreg_b32 %0, hwreg(20, 0, 32)" : "=s"(xcc)); // HW_REG_XCC_ID
        xcc &= 7u;
        const unsigned int slot = atomicAdd(&ctl[xcc], 1u) + 1u;   // 0-based
        const unsigned int grp = slot >> 5, lig = slot & 31u;
        const unsigned int mytag = (xcc << 8) | grp;
        if (lig == 31u) {                       // 32nd member: claim a direction
            const unsigned int dcl = atomicAdd(&ctl[8], 1u) + 1u;
            if (dcl < 2u)
                __hip_atomic_store(&ctl[9 + dcl], mytag,
                                   __ATOMIC_RELAXED, __HIP_MEMORY_SCOPE_AGENT);
        }
        unsigned int c0, c1;
        do {
            c0 = __hip_atomic_load(&ctl[9],  __ATOMIC_RELAXED, __HIP_MEMORY_SCOPE_AGENT);
            c1 = __hip_atomic_load(&ctl[10], __ATOMIC_RELAXED, __HIP_MEMORY_SCOPE_AGENT);
        } while (c0 == 0xFFFFFFFFu || c1 == 0xFFFFFFFFu);
        int role = -1;
        if      (c0 == mytag) role = (int)lig;        // dir 0, k = lig
        else if (c1 == mytag) role = 32 + (int)lig;   // dir 1, k = lig
        s_role = role;
        s_fast = 1;
    }
    __syncthreads();
    const int role = s_role;
    if (role < 0) return;                     // 448 wgs exit here

    const int d = role >> 5;          // 0 fwd, 1 bwd
    const int k = role & 31;
    const float* zin = d ? zin_b : zin_f;
    const float* Whh = d ? Whh_b : Whh_f;
    unsigned int* hw  = d ? hw_b  : hw_f;
    unsigned int* hwl = d ? hwl_b : hwl_f;

    const int tid = threadIdx.x;
    const int q = tid >> 6;          // wave = column segment (128 cols)
    const int r = tid & 63;          // gate row within wg
    const int gate = r >> 4, jj = r & 15;
    const int grow = gate * HH + k * 16 + jj;      // global gate row [0,2048)

    const f4* wp = (const f4*)(Whh + (size_t)grow * HH + q * 128);
    f4 w[32];
#pragma unroll
    for (int i = 0; i < 32; ++i) w[i] = wp[i];     // plain loads: correct waitcnt
#pragma unroll
    for (int i = 0; i < 32; ++i)
        asm volatile("" : "+a"(w[i]));             // home the values in AGPRs

    __shared__ float hs[HH];
    __shared__ float zb[256];

    float c = 0.f;
    const int l = tid;               // wave0 lane id (used when tid<64)
    const int g = l >> 4, j = l & 15;     // gate / unit for gate phase
    const int n16 = k * 16 + j;           // hidden index for gate phase

#define BASE_PROBE() \
    asm volatile( \
        "global_load_dwordx4 %0, %2, off sc0 sc1\n\t" \
        "global_load_dwordx4 %1, %2, off offset:16 sc0 sc1\n\t" \
        "s_waitcnt vmcnt(0)" \
        : "=v"(a0), "=v"(a1) : "v"(pa) : "memory")
#define BP_OK (a0.x != SENT && a0.y != SENT && a0.z != SENT && a0.w != SENT && \
               a1.x != SENT && a1.y != SENT && a1.z != SENT && a1.w != SENT)
#define FAST_PROBE() \
    asm volatile( \
        "global_atomic_add_x2 %0, %4, %5, off sc0\n\t" \
        "global_atomic_add_x2 %1, %4, %5, off offset:8 sc0\n\t" \
        "global_atomic_add_x2 %2, %4, %5, off offset:16 sc0\n\t" \
        "global_atomic_add_x2 %3, %4, %5, off offset:24 sc0\n\t" \
        "s_waitcnt vmcnt(0)" \
        : "=&v"(f0), "=&v"(f1), "=&v"(f2), "=&v"(f3) \
        : "v"(pl), "v"(zz) : "memory")
#define FP_OK (f0.x != SENT && f0.y != SENT && f1.x != SENT && f1.y != SENT && \
               f2.x != SENT && f2.y != SENT && f3.x != SENT && f3.y != SENT)
#define PACK() do { a0 = (u4){f0.x, f0.y, f1.x, f1.y}; \
                    a1 = (u4){f2.x, f2.y, f3.x, f3.y}; } while (0)

    for (int it = 0; it < TT; ++it) {
        const int t = d ? (TT - 1 - it) : it;

        // wave0: zin value for (gate g, unit j) — issued before the poll
        float z = 0.f;
        if (tid < 64) z = zin[(size_t)t * G4 + g * HH + n16];

        if (it > 0 && tid < 64) {
            const int tp = d ? (t + 1) : (t - 1);
            const unsigned int* pa = hw  + (size_t)tp * HH + l * 8;
            const unsigned int* pl = hwl + (size_t)tp * HH + l * 8;
            u4 a0, a1;
            u2 f0, f1, f2, f3;
            const u2 zz = {0u, 0u};
            bool got = false;
            if (s_fast) {
                if (it == 1) {
                    // classify: fast (local L2) vs base (MALL); see header.
                    for (;;) {
                        FAST_PROBE();
                        if (FP_OK) { PACK(); got = true; break; }
                        BASE_PROBE();
                        if (BP_OK) {
                            FAST_PROBE();
                            if (!FP_OK) s_fast = 0;   // cross-XCD placement
                            got = true;               // a0,a1 valid from base
                            break;
                        }
                    }
                } else {
                    int spins = 0;
                    for (;;) {
                        FAST_PROBE();
                        if (FP_OK) { PACK(); got = true; break; }
                        if (++spins > 16384) { s_fast = 0; break; }
                    }
                }
            }
            if (!got) {
                for (;;) { BASE_PROBE(); if (BP_OK) break; }   // R0-proven path
            }
            u4* hd = (u4*)(hs + l * 8);
            hd[0] = a0; hd[1] = a1;
        }
        __syncthreads();                                   // B1: hs ready

        // keep weights homed in AGPRs across the loop (re-pin each iter)
#pragma unroll
        for (int i = 0; i < 32; ++i) asm volatile("" : "+a"(w[i]));

        float part = 0.f;
        if (it > 0) {
            const f4* hv = ((const f4*)hs) + (q << 5);     // wave-uniform broadcast
#pragma unroll
            for (int i = 0; i < 32; ++i) {
                f4 h4 = hv[i];
                part += w[i].x * h4.x + w[i].y * h4.y + w[i].z * h4.z + w[i].w * h4.w;
            }
        }
        zb[tid] = part;                                    // zb[q*64 + r]
        __syncthreads();                                   // B2: partials ready

        if (tid < 64) {
            // same summation order as R6 (bit-exact): qq = 0..3
            float s = zb[l] + zb[64 + l] + zb[128 + l] + zb[192 + l];
            const float pre = z + s;
            float act;
            if (g == 2) act = tanhf(pre);                  // g gate
            else        act = 1.f / (1.f + expf(-pre));    // i, f, o gates
            const float gi = __shfl(act, j);
            const float gf = __shfl(act, j + 16);
            const float gg = __shfl(act, j + 32);
            const float go = __shfl(act, j + 48);
            if (l < 16) {
                c = gf * c + gi * gg;
                const float hval = go * tanhf(c);
                unsigned int hvbits = __float_as_uint(hval);
                unsigned int* hp  = &hw [(size_t)t * HH + k * 16 + l];
                unsigned int* hlp = &hwl[(size_t)t * HH + k * 16 + l];
                // plain store first (write-through -> local L2, fast path),
                // then the R0-proven device-scope store (MALL, base path).
                asm volatile(
                    "global_store_dword %0, %2, off\n\t"
                    "global_store_dword %1, %2, off sc1"
                    :: "v"(hlp), "v"(hp), "v"(hvbits) : "memory");
            }
        }
        // 2 barriers suffice: hs(it+1) writes (wave0, after B2(it)) cannot
        // race dot reads of hs(it) (before B2(it)); zb(it+1) writes (after
        // B1(it+1)) cannot race gate-phase zb reads (wave0 reaches B1(it+1)
        // only after finishing them).
    }
#undef BASE_PROBE
#undef BP_OK
#undef FAST_PROBE
#undef FP_OK
#undef PACK
}

// ---------------------------------------------------------------------------
// Kernel 3: feats[t] = [h_f[t] | h_b[t]] . fc_w[i] + fc_b[i].  One wave per t.
// ---------------------------------------------------------------------------
__global__ void feats_kernel(const float* __restrict__ h_f, const float* __restrict__ h_b,
                             const float* __restrict__ fc_w, const float* __restrict__ fc_b,
                             float* __restrict__ feats)
{
    const int t = blockIdx.x;
    const int l = threadIdx.x;
    float acc[NC] = {0.f, 0.f, 0.f, 0.f, 0.f};
    for (int m = 0; m < 16; ++m) {
        const int cg = l + m * 64;
        const float hv = (cg < HH) ? h_f[(size_t)t * HH + cg]
                                   : h_b[(size_t)t * HH + cg - HH];
#pragma unroll
        for (int i = 0; i < NC; i++) acc[i] += hv * fc_w[i * (2 * HH) + cg];
    }
#pragma unroll
    for (int i = 0; i < NC; i++) {
#pragma unroll
        for (int off = 32; off; off >>= 1) acc[i] += __shfl_xor(acc[i], off);
    }
    if (l == 0) {
#pragma unroll
        for (int i = 0; i < NC; i++) feats[(size_t)t * NC + i] = acc[i] + fc_b[i];
    }
}

// ---------------------------------------------------------------------------
// Kernel 4: Viterbi forward + backtrack. 1 block, 64 threads.
// ---------------------------------------------------------------------------
__global__ void viterbi_kernel(const float* __restrict__ feats,
                               const float* __restrict__ trans,
                               float* __restrict__ out)
{
    __shared__ float fs[TT * NC];
    __shared__ int par[TT];
    __shared__ float pathv[TT];
    const int tid = threadIdx.x;
    for (int i = tid; i < TT * NC; i += 64) fs[i] = feats[i];
    float tr[25];
#pragma unroll
    for (int i = 0; i < 25; i++) tr[i] = trans[i];
    __syncthreads();

    float layer[NC];
#pragma unroll
    for (int i = 0; i < NC; i++) layer[i] = fs[i] + tr[i * 5 + 3];

    for (int s = 0; s < TT - 1; ++s) {
        const float* ft = &fs[(s + 1) * NC];
        float nl[NC]; int pk = 0;
#pragma unroll
        for (int i = 0; i < NC; i++) {
            float best = tr[i * 5 + 0] + layer[0]; int bj = 0;
#pragma unroll
            for (int jj = 1; jj < NC; jj++) {
                const float v = tr[i * 5 + jj] + layer[jj];
                if (v > best) { best = v; bj = jj; }
            }
            nl[i] = ft[i] + best;
            pk |= bj << (3 * i);
        }
#pragma unroll
        for (int i = 0; i < NC; i++) layer[i] = nl[i];
        if (tid == 0) par[s] = pk;
    }
    float best = layer[0] + tr[20]; int idx0 = 0;
#pragma unroll
    for (int jj = 1; jj < NC; jj++) {
        const float v = layer[jj] + tr[20 + jj];
        if (v > best) { best = v; idx0 = jj; }
    }
    __syncthreads();
    if (tid == 0) {
        pathv[TT - 1] = (float)idx0;
        int idx = idx0;
        for (int s = TT - 2; s >= 0; --s) {
            idx = (par[s] >> (3 * idx)) & 7;
            pathv[s] = (float)idx;
        }
        out[TT] = best;
    }
    __syncthreads();
    for (int i = tid; i < TT; i += 64) out[i] = pathv[i];
}

// ---------------------------------------------------------------------------
extern "C" void kernel_launch(void* const* d_in, const int* in_sizes, int n_in,
                              void* d_out, int out_size, void* d_ws, size_t ws_size,
                              hipStream_t stream) {
    const int*   sent   = (const int*)d_in[0];
    const float* emb    = (const float*)d_in[1];
    const float* Wih_f  = (const float*)d_in[2];
    const float* Whh_f  = (const float*)d_in[3];
    const float* bih_f  = (const float*)d_in[4];
    const float* bhh_f  = (const float*)d_in[5];
    const float* Wih_b  = (const float*)d_in[6];
    const float* Whh_b  = (const float*)d_in[7];
    const float* bih_b  = (const float*)d_in[8];
    const float* bhh_b  = (const float*)d_in[9];
    const float* fc_w   = (const float*)d_in[10];
    const float* fc_b   = (const float*)d_in[11];
    const float* trans  = (const float*)d_in[12];
    float* out = (float*)d_out;

    char* ws = (char*)d_ws;
    float* zin_f = (float*)ws;                                    // 16 MB @ 0
    float* zin_b = (float*)(ws + (size_t)16777216);               // 16 MB @ 16M
    unsigned int* hw_f  = (unsigned int*)(ws + (size_t)33554432); //  4 MB @ 32M (device copy)
    unsigned int* hw_b  = (unsigned int*)(ws + (size_t)37748736); //  4 MB @ 36M
    unsigned int* hwl_f = (unsigned int*)(ws + (size_t)41943040); //  4 MB @ 40M (XCD-local fast copy)
    unsigned int* hwl_b = (unsigned int*)(ws + (size_t)46137344); //  4 MB @ 44M
    float* feats = (float*)(ws + (size_t)50331648);               // 40 KB @ 48M
    unsigned int* ctl = (unsigned int*)(ws + (size_t)50372608);   // 128 B claim ctl

    // OWN the sentinel: hw_f, hw_b, hwl_f, hwl_b = 0xFFFFFFFF (contiguous 16MB)
    hipMemsetAsync(hw_f, 0xFF, (size_t)16777216, stream);
    // claim control block: counters start at -1, chosen tags at sentinel
    hipMemsetAsync(ctl, 0xFF, (size_t)128, stream);

    dim3 gg(G4 / 128, TT / 128, 2);
    zin_gemm<<<gg, 256, 0, stream>>>(sent, emb, Wih_f, bih_f, bhh_f,
                                     Wih_b, bih_b, bhh_b, zin_f, zin_b);

    lstm_rec<<<512, 256, 0, stream>>>(zin_f, zin_b, Whh_f, Whh_b,
                                      hw_f, hw_b, hwl_f, hwl_b, ctl);

    feats_kernel<<<TT, 64, 0, stream>>>((const float*)hw_f, (const float*)hw_b,
                                        fc_w, fc_b, feats);

    viterbi_kernel<<<1, 64, 0, stream>>>(feats, trans, out);
}

// Round 3
// 5221.540 us; speedup vs baseline: 3.2331x; 3.2331x over previous
//
#include <hip/hip_runtime.h>

#define TT 2048
#define WD 768
#define HH 512
#define G4 2048      // 4*H
#define NC 5
#define SENT 0xFFFFFFFFu   // owned sentinel (-NaN); |h|<1 can never produce it.
                           // h buffers memset to 0xFF at every launch.

typedef float f4 __attribute__((ext_vector_type(4)));
typedef unsigned int u4 __attribute__((ext_vector_type(4)));
typedef unsigned int u2 __attribute__((ext_vector_type(2)));

// ---------------------------------------------------------------------------
// Kernel 1: zin[t][g] = emb[sent[t]] . Wih[g] + bih[g] + bhh[g]   (both dirs)
// ---------------------------------------------------------------------------
__global__ __launch_bounds__(256) void zin_gemm(
    const int* __restrict__ sent, const float* __restrict__ emb,
    const float* __restrict__ Wih_f, const float* __restrict__ bih_f, const float* __restrict__ bhh_f,
    const float* __restrict__ Wih_b, const float* __restrict__ bih_b, const float* __restrict__ bhh_b,
    float* __restrict__ zin_f, float* __restrict__ zin_b)
{
    const int dirn = blockIdx.z;
    const float* Wih = dirn ? Wih_b : Wih_f;
    const float* bih = dirn ? bih_b : bih_f;
    const float* bhh = dirn ? bhh_b : bhh_f;
    float* zin = dirn ? zin_b : zin_f;

    __shared__ float As[16][128];
    __shared__ float Bs[16][128];

    const int tid = threadIdx.x;
    const int t0 = blockIdx.y * 128;
    const int g0 = blockIdx.x * 128;
    const int tm = tid >> 4, tn = tid & 15;

    float acc[8][8];
#pragma unroll
    for (int a = 0; a < 8; a++)
#pragma unroll
        for (int b = 0; b < 8; b++) acc[a][b] = 0.f;

    for (int kt = 0; kt < 48; ++kt) {
        const int k0 = kt * 16;
#pragma unroll
        for (int u = 0; u < 2; ++u) {
            const int s = tid * 2 + u;
            const int m = s >> 2, kq = s & 3;
            const int rowA = sent[t0 + m];
            float4 av = *(const float4*)(emb + (size_t)rowA * WD + k0 + kq * 4);
            As[kq * 4 + 0][m] = av.x; As[kq * 4 + 1][m] = av.y;
            As[kq * 4 + 2][m] = av.z; As[kq * 4 + 3][m] = av.w;
            float4 bv = *(const float4*)(Wih + (size_t)(g0 + m) * WD + k0 + kq * 4);
            Bs[kq * 4 + 0][m] = bv.x; Bs[kq * 4 + 1][m] = bv.y;
            Bs[kq * 4 + 2][m] = bv.z; Bs[kq * 4 + 3][m] = bv.w;
        }
        __syncthreads();
#pragma unroll
        for (int kk = 0; kk < 16; ++kk) {
            float4 a0 = *(const float4*)&As[kk][tm * 8];
            float4 a1 = *(const float4*)&As[kk][tm * 8 + 4];
            float4 b0 = *(const float4*)&Bs[kk][tn * 8];
            float4 b1 = *(const float4*)&Bs[kk][tn * 8 + 4];
            float av8[8] = {a0.x, a0.y, a0.z, a0.w, a1.x, a1.y, a1.z, a1.w};
            float bv8[8] = {b0.x, b0.y, b0.z, b0.w, b1.x, b1.y, b1.z, b1.w};
#pragma unroll
            for (int a = 0; a < 8; a++)
#pragma unroll
                for (int b = 0; b < 8; b++) acc[a][b] += av8[a] * bv8[b];
        }
        __syncthreads();
    }
    float bias[8];
#pragma unroll
    for (int b = 0; b < 8; b++) { int g = g0 + tn * 8 + b; bias[b] = bih[g] + bhh[g]; }
#pragma unroll
    for (int a = 0; a < 8; a++) {
        const int t = t0 + tm * 8 + a;
        float* op = zin + (size_t)t * G4 + g0 + tn * 8;
        float4 o0 = {acc[a][0] + bias[0], acc[a][1] + bias[1], acc[a][2] + bias[2], acc[a][3] + bias[3]};
        float4 o1 = {acc[a][4] + bias[4], acc[a][5] + bias[5], acc[a][6] + bias[6], acc[a][7] + bias[7]};
        *(float4*)op = o0; *(float4*)(op + 4) = o1;
    }
}

// ---------------------------------------------------------------------------
// Kernel 2: LSTM recurrence — R0 protocol, restructured topology.
//
// R1/R2 lesson: plain agent-scope store + sc0 sc1 poll load is the ONLY
// proven-fast visibility path (sc0-only = stale L1; atomic probes = L2
// serialization + 1.7 GB writeback). So keep R0's memory protocol exactly
// and remove R0's structural waste instead:
//
//  * Per-wave chunked polling: wave q's dot only reads h units
//    [q*128,(q+1)*128) = producers 8q..8q+7. Each wave polls its own chunk
//    (8B/lane), writes its own LDS region, wave-synchronous -> B1 is GONE.
//    Each wave waits on 8 producers, not 32; waves 1-3 poll concurrently
//    with wave0's gate phase instead of idling at B1.
//  * 2-deep pipelined probes with vmcnt(1): detection period ~RT/2 instead
//    of RT. Both probe buffers sentinel-inited each step, so any vmcnt
//    misaccount degrades to an extra spin (values are write-once) — never a
//    false pass.
//  * h rows padded to one 128B line per producer (no cross-XCD false
//    sharing on store merge): layout hw[t][32 producers][32 dwords(16 used)].
//  * zb ping-pong (zb[2][256]) closes the cross-iteration race that B1's
//    removal opens. ONE barrier per step total.
//
// Numerics (summation order, gate formulas) bit-identical to R0.
// ---------------------------------------------------------------------------
__global__ __launch_bounds__(256, 1) void lstm_rec(
    const float* __restrict__ zin_f, const float* __restrict__ zin_b,
    const float* __restrict__ Whh_f, const float* __restrict__ Whh_b,
    unsigned int* __restrict__ hw_f, unsigned int* __restrict__ hw_b)
{
    const int bid = blockIdx.x;
    const int d = bid >> 5;          // 0 fwd, 1 bwd
    const int k = bid & 31;
    const float* zin = d ? zin_b : zin_f;
    const float* Whh = d ? Whh_b : Whh_f;
    unsigned int* hw = d ? hw_b : hw_f;

    const int tid = threadIdx.x;
    const int q = tid >> 6;          // wave = column segment (128 cols)
    const int r = tid & 63;          // gate row within wg
    const int gate = r >> 4, jj = r & 15;
    const int grow = gate * HH + k * 16 + jj;      // global gate row [0,2048)

    const f4* wp = (const f4*)(Whh + (size_t)grow * HH + q * 128);
    f4 w[32];
#pragma unroll
    for (int i = 0; i < 32; ++i) w[i] = wp[i];     // plain loads: correct waitcnt
#pragma unroll
    for (int i = 0; i < 32; ++i)
        asm volatile("" : "+a"(w[i]));             // home the values in AGPRs

    __shared__ float hs[HH];
    __shared__ float zb[2][256];

    float c = 0.f;
    const int l = tid;               // wave0 lane id (used when tid<64)
    const int g = l >> 4, j = l & 15;     // gate / unit for gate phase
    const int n16 = k * 16 + j;           // hidden index for gate phase

    // poll geometry: wave q, lane r -> producer p = 8q + (r>>3), dwords (r&7)*2..+1
    const int pprod = 8 * q + (r >> 3);
    const int pland = (r & 7) * 2;
    // LDS float2 slot for this lane's 2 h values (dense chunk q)
    float2* const hslot = (float2*)hs + (q * 64 + (r >> 3) * 8 + (r & 7));

#define PROBE(dst) \
    asm volatile("global_load_dwordx2 %0, %1, off sc0 sc1" \
                 : "+v"(dst) : "v"(pp) : "memory")
#define WAITV1() asm volatile("s_waitcnt vmcnt(1)" ::: "memory")
#define WAITV0() asm volatile("s_waitcnt vmcnt(0)" ::: "memory")

    for (int it = 0; it < TT; ++it) {
        const int t = d ? (TT - 1 - it) : it;

        // wave0: zin value for (gate g, unit j) — plain load, issued first so
        // its HBM latency overlaps the poll ("memory"-clobbered asm below
        // cannot be hoisted above it, nor it sunk below them).
        float z = 0.f;
        if (tid < 64) z = zin[(size_t)t * G4 + g * HH + n16];

        if (it > 0) {
            const int tp = d ? (t + 1) : (t - 1);
            const unsigned int* pp = hw + (size_t)tp * 1024 + pprod * 32 + pland;
            u2 va = {SENT, SENT}, vb = {SENT, SENT};
            u2 hv2;
            PROBE(va);
            for (;;) {
                PROBE(vb);
                WAITV1();                               // va (and wave0's z) landed
                if (__all(va.x != SENT && va.y != SENT)) { hv2 = va; WAITV0(); break; }
                PROBE(va);
                WAITV1();                               // vb landed
                if (__all(vb.x != SENT && vb.y != SENT)) { hv2 = vb; WAITV0(); break; }
            }
            *hslot = (float2){__uint_as_float(hv2.x), __uint_as_float(hv2.y)};
            // wave-synchronous: compiler inserts lgkmcnt before the dot's
            // ds_reads; no barrier needed (chunk q is wave-q-private).
        }

        // keep weights homed in AGPRs across the loop (re-pin each iter)
#pragma unroll
        for (int i = 0; i < 32; ++i) asm volatile("" : "+a"(w[i]));

        float part = 0.f;
        if (it > 0) {
            const f4* hv = ((const f4*)hs) + (q << 5);     // own chunk only
#pragma unroll
            for (int i = 0; i < 32; ++i) {
                f4 h4 = hv[i];
                part += w[i].x * h4.x + w[i].y * h4.y + w[i].z * h4.z + w[i].w * h4.w;
            }
        }
        zb[it & 1][tid] = part;
        __syncthreads();                                   // B2: partials ready

        if (tid < 64) {
            // same summation order as R0 (bit-exact): qq = 0..3
            const float* zbc = zb[it & 1];
            float s = zbc[l] + zbc[64 + l] + zbc[128 + l] + zbc[192 + l];
            const float pre = z + s;
            float act;
            if (g == 2) act = tanhf(pre);                  // g gate
            else        act = 1.f / (1.f + expf(-pre));    // i, f, o gates
            const float gi = __shfl(act, j);
            const float gf = __shfl(act, j + 16);
            const float gg = __shfl(act, j + 32);
            const float go = __shfl(act, j + 48);
            if (l < 16) {
                c = gf * c + gi * gg;
                const float hval = go * tanhf(c);
                __hip_atomic_store(&hw[(size_t)t * 1024 + k * 32 + l],
                                   __float_as_uint(hval),
                                   __ATOMIC_RELAXED, __HIP_MEMORY_SCOPE_AGENT);
            }
        }
        // Cross-iteration safety without B1:
        //  * hs chunk q: written and read only by wave q, in program order.
        //  * zb: it+1 writes go to zb[(it+1)&1] != zb[it&1] read by wave0.
        //  * wave q at it+1 cannot overwrite anything it or others still read.
    }
#undef PROBE
#undef WAITV1
#undef WAITV0
}

// ---------------------------------------------------------------------------
// Kernel 3: feats[t] = [h_f[t] | h_b[t]] . fc_w[i] + fc_b[i].  One wave per t.
// h layout is line-padded: hw[t][32 producers][32 dwords (16 used)].
// ---------------------------------------------------------------------------
__global__ void feats_kernel(const float* __restrict__ h_f, const float* __restrict__ h_b,
                             const float* __restrict__ fc_w, const float* __restrict__ fc_b,
                             float* __restrict__ feats)
{
    const int t = blockIdx.x;
    const int l = threadIdx.x;
    float acc[NC] = {0.f, 0.f, 0.f, 0.f, 0.f};
    for (int m = 0; m < 16; ++m) {
        const int cg = l + m * 64;
        const int cu = (cg < HH) ? cg : cg - HH;
        const size_t off = (size_t)t * 1024 + (cu >> 4) * 32 + (cu & 15);
        const float hv = (cg < HH) ? h_f[off] : h_b[off];
#pragma unroll
        for (int i = 0; i < NC; i++) acc[i] += hv * fc_w[i * (2 * HH) + cg];
    }
#pragma unroll
    for (int i = 0; i < NC; i++) {
#pragma unroll
        for (int off = 32; off; off >>= 1) acc[i] += __shfl_xor(acc[i], off);
    }
    if (l == 0) {
#pragma unroll
        for (int i = 0; i < NC; i++) feats[(size_t)t * NC + i] = acc[i] + fc_b[i];
    }
}

// ---------------------------------------------------------------------------
// Kernel 4: Viterbi forward + backtrack. 1 block, 64 threads.
// ---------------------------------------------------------------------------
__global__ void viterbi_kernel(const float* __restrict__ feats,
                               const float* __restrict__ trans,
                               float* __restrict__ out)
{
    __shared__ float fs[TT * NC];
    __shared__ int par[TT];
    __shared__ float pathv[TT];
    const int tid = threadIdx.x;
    for (int i = tid; i < TT * NC; i += 64) fs[i] = feats[i];
    float tr[25];
#pragma unroll
    for (int i = 0; i < 25; i++) tr[i] = trans[i];
    __syncthreads();

    float layer[NC];
#pragma unroll
    for (int i = 0; i < NC; i++) layer[i] = fs[i] + tr[i * 5 + 3];

    for (int s = 0; s < TT - 1; ++s) {
        const float* ft = &fs[(s + 1) * NC];
        float nl[NC]; int pk = 0;
#pragma unroll
        for (int i = 0; i < NC; i++) {
            float best = tr[i * 5 + 0] + layer[0]; int bj = 0;
#pragma unroll
            for (int jj = 1; jj < NC; jj++) {
                const float v = tr[i * 5 + jj] + layer[jj];
                if (v > best) { best = v; bj = jj; }
            }
            nl[i] = ft[i] + best;
            pk |= bj << (3 * i);
        }
#pragma unroll
        for (int i = 0; i < NC; i++) layer[i] = nl[i];
        if (tid == 0) par[s] = pk;
    }
    float best = layer[0] + tr[20]; int idx0 = 0;
#pragma unroll
    for (int jj = 1; jj < NC; jj++) {
        const float v = layer[jj] + tr[20 + jj];
        if (v > best) { best = v; idx0 = jj; }
    }
    __syncthreads();
    if (tid == 0) {
        pathv[TT - 1] = (float)idx0;
        int idx = idx0;
        for (int s = TT - 2; s >= 0; --s) {
            idx = (par[s] >> (3 * idx)) & 7;
            pathv[s] = (float)idx;
        }
        out[TT] = best;
    }
    __syncthreads();
    for (int i = tid; i < TT; i += 64) out[i] = pathv[i];
}

// ---------------------------------------------------------------------------
extern "C" void kernel_launch(void* const* d_in, const int* in_sizes, int n_in,
                              void* d_out, int out_size, void* d_ws, size_t ws_size,
                              hipStream_t stream) {
    const int*   sent   = (const int*)d_in[0];
    const float* emb    = (const float*)d_in[1];
    const float* Wih_f  = (const float*)d_in[2];
    const float* Whh_f  = (const float*)d_in[3];
    const float* bih_f  = (const float*)d_in[4];
    const float* bhh_f  = (const float*)d_in[5];
    const float* Wih_b  = (const float*)d_in[6];
    const float* Whh_b  = (const float*)d_in[7];
    const float* bih_b  = (const float*)d_in[8];
    const float* bhh_b  = (const float*)d_in[9];
    const float* fc_w   = (const float*)d_in[10];
    const float* fc_b   = (const float*)d_in[11];
    const float* trans  = (const float*)d_in[12];
    float* out = (float*)d_out;

    char* ws = (char*)d_ws;
    float* zin_f = (float*)ws;                                    // 16 MB @ 0
    float* zin_b = (float*)(ws + (size_t)16777216);               // 16 MB @ 16M
    unsigned int* hw_f  = (unsigned int*)(ws + (size_t)33554432); //  8 MB @ 32M (padded: [t][32][32])
    unsigned int* hw_b  = (unsigned int*)(ws + (size_t)41943040); //  8 MB @ 40M
    float* feats = (float*)(ws + (size_t)50331648);               // 40 KB @ 48M

    // OWN the sentinel: hw_f + hw_b = 0xFFFFFFFF (contiguous 16 MB)
    hipMemsetAsync(hw_f, 0xFF, (size_t)16777216, stream);

    dim3 gg(G4 / 128, TT / 128, 2);
    zin_gemm<<<gg, 256, 0, stream>>>(sent, emb, Wih_f, bih_f, bhh_f,
                                     Wih_b, bih_b, bhh_b, zin_f, zin_b);

    lstm_rec<<<64, 256, 0, stream>>>(zin_f, zin_b, Whh_f, Whh_b, hw_f, hw_b);

    feats_kernel<<<TT, 64, 0, stream>>>((const float*)hw_f, (const float*)hw_b,
                                        fc_w, fc_b, feats);

    viterbi_kernel<<<1, 64, 0, stream>>>(feats, trans, out);
}